// Round 6
// baseline (1421.767 us; speedup 1.0000x reference)
//
#include <hip/hip_runtime.h>
#include <math.h>

#define HH 16
#define DD 64
#define TT 2048
#define BB 4
#define CC 1024
#define MM (BB*TT)   // 8192

typedef __attribute__((ext_vector_type(8))) short short8;     // 8 bf16 (4 VGPRs)
typedef __attribute__((ext_vector_type(4))) float f32x4;      // MFMA C/D
typedef __attribute__((ext_vector_type(8))) unsigned short bfu8;
typedef __attribute__((ext_vector_type(4))) unsigned short bfu4;

__device__ __forceinline__ unsigned short f2bf(float f) {
    unsigned int u = __builtin_bit_cast(unsigned int, f);
    unsigned int r = (u + 0x7fffu + ((u >> 16) & 1u)) >> 16;   // RNE
    return (unsigned short)r;
}
__device__ __forceinline__ float bf2f(unsigned short s) {
    unsigned int u = ((unsigned int)s) << 16;
    return __builtin_bit_cast(float, u);
}

// ---------------------------------------------------------------------------
// x fp32 [M][C] -> bf16 same layout. 8 elems/thread.
// ---------------------------------------------------------------------------
__global__ __launch_bounds__(256) void convert_x(
    const float* __restrict__ x, unsigned short* __restrict__ xb)
{
    const size_t i = (size_t)blockIdx.x * 256 + threadIdx.x;
    const float4 a = ((const float4*)x)[i * 2];
    const float4 b = ((const float4*)x)[i * 2 + 1];
    bfu8 o;
    o[0] = f2bf(a.x); o[1] = f2bf(a.y); o[2] = f2bf(a.z); o[3] = f2bf(a.w);
    o[4] = f2bf(b.x); o[5] = f2bf(b.y); o[6] = f2bf(b.z); o[7] = f2bf(b.w);
    *(bfu8*)(xb + i * 8) = o;
}

// ---------------------------------------------------------------------------
// W [K][N] fp32 -> Wt [N][K] bf16 (transposed), z selects one of 4 matrices.
// 64x64 tiles via LDS.
// ---------------------------------------------------------------------------
__global__ __launch_bounds__(256) void transpose_w(
    const float* __restrict__ Wq, const float* __restrict__ Wk,
    const float* __restrict__ Wv, const float* __restrict__ Wo,
    unsigned short* __restrict__ Wt)
{
    __shared__ float st[64][65];
    const int z = blockIdx.z;
    const float* W = (z == 0) ? Wq : (z == 1) ? Wk : (z == 2) ? Wv : Wo;
    unsigned short* out = Wt + (size_t)z * CC * CC;
    const int rb = blockIdx.y * 64, cb = blockIdx.x * 64;
    const int t = threadIdx.x;
    const int tr = t >> 4, tc4 = (t & 15) * 4;
    #pragma unroll
    for (int i = 0; i < 4; ++i) {
        const int r = i * 16 + tr;
        const float4 v = *(const float4*)&W[(size_t)(rb + r) * CC + cb + tc4];
        st[r][tc4 + 0] = v.x; st[r][tc4 + 1] = v.y;
        st[r][tc4 + 2] = v.z; st[r][tc4 + 3] = v.w;
    }
    __syncthreads();
    #pragma unroll
    for (int i = 0; i < 4; ++i) {
        const int c = i * 16 + tr;             // output row = original column
        bfu4 o;
        o[0] = f2bf(st[tc4 + 0][c]); o[1] = f2bf(st[tc4 + 1][c]);
        o[2] = f2bf(st[tc4 + 2][c]); o[3] = f2bf(st[tc4 + 3][c]);
        *(bfu4*)&out[(size_t)(cb + c) * CC + rb + tc4] = o;
    }
}

// ---------------------------------------------------------------------------
// RoPE tables: tab[t*32 + p] = (cos, sin) of t * theta^(-2p/64).
// ---------------------------------------------------------------------------
__global__ __launch_bounds__(256) void rope_tables(float2* __restrict__ tab)
{
    const int i = blockIdx.x * 256 + threadIdx.x;   // 65536 total
    const int t = i >> 5, p = i & 31;
    const float inv_freq = expf(-(float)(2 * p) * (9.210340371976184f / 64.0f));
    const float ang = (float)t * inv_freq;
    float s, c;
    sincosf(ang, &s, &c);
    tab[i] = make_float2(c, s);
}

// ---------------------------------------------------------------------------
// MFMA GEMM, m97 structure: 128x128 tile, BK=32, 4 waves (2x2), 4x4 frags of
// 16x16x32 bf16 per wave, global_load_lds width-16 staging, linear LDS.
// A [M][K] bf16 row-major; B given TRANSPOSED: Wt [N][K] bf16.
// MODE 1: z = blockIdx.z in {0,1,2} selects Wq/Wk/Wv slab; RoPE for z<2;
//         writes bf16 [B][H][T][D] at qkv + z*M*C.
// MODE 0: writes fp32 out[M][C] = A@B + bias.
// ---------------------------------------------------------------------------
template<int MODE>
__global__ __launch_bounds__(256) void gemm_mfma(
    const unsigned short* __restrict__ A,
    const unsigned short* __restrict__ Wt,
    const float* __restrict__ bias,
    const float2* __restrict__ tab,
    void* __restrict__ outv)
{
    __shared__ short lds[128 * 32 * 2];        // A tile | B tile, 16 KiB
    short* As = lds;
    short* Bs = lds + 128 * 32;

    const int tid  = threadIdx.x;
    const int lane = tid & 63;
    const int w    = tid >> 6;                 // wave id 0..3
    const int wr   = w >> 1, wc = w & 1;       // 2x2 wave grid
    const int mb   = blockIdx.y * 128, nb = blockIdx.x * 128;
    const int z    = (MODE == 1) ? blockIdx.z : 0;
    const unsigned short* Bmat = Wt + (size_t)z * CC * CC;

    f32x4 acc[4][4] = {};

    for (int k0 = 0; k0 < CC; k0 += 32) {
        __syncthreads();                        // LDS safe to overwrite
        #pragma unroll
        for (int t2 = 0; t2 < 2; ++t2) {
            const int ci  = w * 128 + t2 * 64 + lane;   // chunk 0..511
            const int row = ci >> 2, kc = ci & 3;
            const unsigned short* ga = A    + (size_t)(mb + row) * CC + k0 + kc * 8;
            const unsigned short* gb = Bmat + (size_t)(nb + row) * CC + k0 + kc * 8;
            __builtin_amdgcn_global_load_lds(
                (const __attribute__((address_space(1))) unsigned int*)ga,
                (__attribute__((address_space(3))) unsigned int*)(As + (w * 2 + t2) * 512),
                16, 0, 0);
            __builtin_amdgcn_global_load_lds(
                (const __attribute__((address_space(1))) unsigned int*)gb,
                (__attribute__((address_space(3))) unsigned int*)(Bs + (w * 2 + t2) * 512),
                16, 0, 0);
        }
        __syncthreads();                        // staging data visible

        short8 a[4], b[4];
        #pragma unroll
        for (int i = 0; i < 4; ++i) {
            const int ro = (wr * 64 + i * 16 + (lane & 15)) * 32 + (lane >> 4) * 8;
            a[i] = *(const short8*)&As[ro];
            const int co = (wc * 64 + i * 16 + (lane & 15)) * 32 + (lane >> 4) * 8;
            b[i] = *(const short8*)&Bs[co];
        }
        #pragma unroll
        for (int i = 0; i < 4; ++i)
            #pragma unroll
            for (int j = 0; j < 4; ++j)
                acc[i][j] = __builtin_amdgcn_mfma_f32_16x16x32_bf16(
                    a[i], b[j], acc[i][j], 0, 0, 0);
    }

    // ---------------- epilogue ----------------
    if (MODE == 0) {
        float* out = (float*)outv;
        #pragma unroll
        for (int i = 0; i < 4; ++i) {
            const int m0 = mb + wr * 64 + i * 16 + (lane >> 4) * 4;
            #pragma unroll
            for (int j = 0; j < 4; ++j) {
                const int n = nb + wc * 64 + j * 16 + (lane & 15);
                const float bv = bias[n];
                #pragma unroll
                for (int r = 0; r < 4; ++r)
                    out[(size_t)(m0 + r) * CC + n] = acc[i][j][r] + bv;
            }
        }
    } else {
        unsigned short* dst = (unsigned short*)outv + (size_t)z * MM * CC;
        const bool do_rope = (z < 2);
        #pragma unroll
        for (int i = 0; i < 4; ++i) {
            const int m0 = mb + wr * 64 + i * 16 + (lane >> 4) * 4;
            #pragma unroll
            for (int j = 0; j < 4; ++j) {
                const int n = nb + wc * 64 + j * 16 + (lane & 15);
                const int h = n >> 6, d = n & 63;
                #pragma unroll
                for (int r = 0; r < 4; ++r) {
                    const int m  = m0 + r;
                    const int b_ = m >> 11, t = m & (TT - 1);
                    const float val     = acc[i][j][r];
                    const float partner = __shfl_xor(val, 1);
                    // even lane: val = x0, partner = x1 (pair along d)
                    float r0, r1;
                    if (do_rope) {
                        const float2 cs = tab[t * 32 + (d >> 1)];
                        r0 = val * cs.x - partner * cs.y;
                        r1 = val * cs.y + partner * cs.x;
                    } else {
                        r0 = val; r1 = partner;
                    }
                    if ((lane & 1) == 0) {
                        const unsigned int pk =
                            (unsigned int)f2bf(r0) | ((unsigned int)f2bf(r1) << 16);
                        *(unsigned int*)&dst[(((size_t)(b_ * HH + h) * TT + t) * DD) + (d & ~1)] = pk;
                    }
                }
            }
        }
    }
}

// ---------------------------------------------------------------------------
// Flash-style causal attention, fp32 compute, bf16 I/O.
// 1 thread = 1 q-row; K/V tiles (64 keys) expanded to fp32 in LDS.
// ---------------------------------------------------------------------------
__global__ __launch_bounds__(256) void attn(
    const unsigned short* __restrict__ q, const unsigned short* __restrict__ k,
    const unsigned short* __restrict__ v, unsigned short* __restrict__ att)
{
    __shared__ float kl[64][64];
    __shared__ float vl[64][64];
    const int tid = threadIdx.x;
    const int bh  = blockIdx.x;              // b*H + h
    const int b_  = bh >> 4, h = bh & 15;
    const int r   = blockIdx.y * 256 + tid;  // q row

    const unsigned short* qp = q + ((size_t)bh * TT + r) * DD;
    float qreg[64];
    #pragma unroll
    for (int i = 0; i < 8; ++i) {
        const bfu8 u = *(const bfu8*)(qp + i * 8);
        #pragma unroll
        for (int j = 0; j < 8; ++j) qreg[i * 8 + j] = bf2f(u[j]);
    }

    float o[64];
    #pragma unroll
    for (int d = 0; d < 64; ++d) o[d] = 0.f;
    float mmax = -INFINITY, l = 0.f;

    const int ntiles = blockIdx.y * 4 + 4;
    for (int kt = 0; kt < ntiles; ++kt) {
        const int kbase = kt * 64;
        const unsigned short* kp = k + ((size_t)bh * TT + kbase) * DD;
        const unsigned short* vp = v + ((size_t)bh * TT + kbase) * DD;
        __syncthreads();
        #pragma unroll
        for (int i = 0; i < 2; ++i) {
            const int e   = (tid + i * 256) * 8;     // elem offset in tile
            const int row = e >> 6, col = e & 63;
            const bfu8 ku = *(const bfu8*)(kp + e);
            const bfu8 vu = *(const bfu8*)(vp + e);
            #pragma unroll
            for (int j = 0; j < 8; ++j) {
                kl[row][col + j] = bf2f(ku[j]);
                vl[row][col + j] = bf2f(vu[j]);
            }
        }
        __syncthreads();

        const int lim = min(63, r - kbase);          // causal
        for (int kk = 0; kk <= lim; ++kk) {
            float s = 0.f;
            #pragma unroll
            for (int d = 0; d < 64; ++d) s = fmaf(qreg[d], kl[kk][d], s);
            s *= 0.125f;
            if (s > mmax) {
                const float corr = __expf(mmax - s);
                #pragma unroll
                for (int d = 0; d < 64; ++d) o[d] *= corr;
                l *= corr;
                mmax = s;
            }
            const float p = __expf(s - mmax);
            l += p;
            #pragma unroll
            for (int d = 0; d < 64; ++d) o[d] = fmaf(p, vl[kk][d], o[d]);
        }
    }

    const float inv = 1.0f / l;
    unsigned short* op = att + ((size_t)(b_ * TT + r)) * CC + h * DD;
    #pragma unroll
    for (int i = 0; i < 8; ++i) {
        bfu8 u;
        #pragma unroll
        for (int j = 0; j < 8; ++j) u[j] = f2bf(o[i * 8 + j] * inv);
        *(bfu8*)(op + i * 8) = u;
    }
}

// ---------------------------------------------------------------------------
extern "C" void kernel_launch(void* const* d_in, const int* in_sizes, int n_in,
                              void* d_out, int out_size, void* d_ws, size_t ws_size,
                              hipStream_t stream) {
    const float* x  = (const float*)d_in[0];
    const float* Wq = (const float*)d_in[1];
    const float* Wk = (const float*)d_in[2];
    const float* Wv = (const float*)d_in[3];
    const float* Wo = (const float*)d_in[4];
    const float* bo = (const float*)d_in[5];
    float* out = (float*)d_out;

    char* ws = (char*)d_ws;
    unsigned short* xb  = (unsigned short*)ws;                        // 16 MB
    unsigned short* wt  = (unsigned short*)(ws + (16ull << 20));      //  8 MB (4x [N][K] bf16)
    unsigned short* qkv = (unsigned short*)(ws + (24ull << 20));      // 48 MB (q|k|v, [B][H][T][D])
    unsigned short* aw  = (unsigned short*)(ws + (72ull << 20));      // 16 MB ([M][C] bf16)
    float2*         tab = (float2*)       (ws + (88ull << 20));       // 512 KB

    convert_x  <<<4096, 256, 0, stream>>>(x, xb);
    transpose_w<<<dim3(16, 16, 4), 256, 0, stream>>>(Wq, Wk, Wv, Wo, wt);
    rope_tables<<<256, 256, 0, stream>>>(tab);

    gemm_mfma<1><<<dim3(8, 64, 3), 256, 0, stream>>>(xb, wt, nullptr, tab, qkv);

    const size_t NEL = (size_t)MM * CC;
    attn<<<dim3(BB * HH, TT / 256), 256, 0, stream>>>(
        qkv, qkv + NEL, qkv + 2 * NEL, aw);

    gemm_mfma<0><<<dim3(8, 64), 256, 0, stream>>>(
        aw, wt + 3ull * CC * CC, bo, tab, out);
}

// Round 9
// 464.313 us; speedup vs baseline: 3.0621x; 3.0621x over previous
//
#include <hip/hip_runtime.h>
#include <math.h>

#define HH 16
#define DD 64
#define TT 2048
#define BB 4
#define CC 1024
#define MM (BB*TT)   // 8192

typedef __attribute__((ext_vector_type(8))) short short8;     // 8 bf16 (4 VGPRs)
typedef __attribute__((ext_vector_type(4))) float f32x4;      // MFMA C/D
typedef __attribute__((ext_vector_type(8))) unsigned short bfu8;
typedef __attribute__((ext_vector_type(4))) unsigned short bfu4;

__device__ __forceinline__ unsigned short f2bf(float f) {
    unsigned int u = __builtin_bit_cast(unsigned int, f);
    unsigned int r = (u + 0x7fffu + ((u >> 16) & 1u)) >> 16;   // RNE
    return (unsigned short)r;
}
__device__ __forceinline__ float bf2f(unsigned short s) {
    unsigned int u = ((unsigned int)s) << 16;
    return __builtin_bit_cast(float, u);
}

// ---------------------------------------------------------------------------
// x fp32 [M][C] -> bf16 same layout. 8 elems/thread.
// ---------------------------------------------------------------------------
__global__ __launch_bounds__(256) void convert_x(
    const float* __restrict__ x, unsigned short* __restrict__ xb)
{
    const size_t i = (size_t)blockIdx.x * 256 + threadIdx.x;
    const float4 a = ((const float4*)x)[i * 2];
    const float4 b = ((const float4*)x)[i * 2 + 1];
    bfu8 o;
    o[0] = f2bf(a.x); o[1] = f2bf(a.y); o[2] = f2bf(a.z); o[3] = f2bf(a.w);
    o[4] = f2bf(b.x); o[5] = f2bf(b.y); o[6] = f2bf(b.z); o[7] = f2bf(b.w);
    *(bfu8*)(xb + i * 8) = o;
}

// ---------------------------------------------------------------------------
// W [K][N] fp32 -> Wt [N][K] bf16 (transposed), z selects one of 4 matrices.
// ---------------------------------------------------------------------------
__global__ __launch_bounds__(256) void transpose_w(
    const float* __restrict__ Wq, const float* __restrict__ Wk,
    const float* __restrict__ Wv, const float* __restrict__ Wo,
    unsigned short* __restrict__ Wt)
{
    __shared__ float st[64][65];
    const int z = blockIdx.z;
    const float* W = (z == 0) ? Wq : (z == 1) ? Wk : (z == 2) ? Wv : Wo;
    unsigned short* out = Wt + (size_t)z * CC * CC;
    const int rb = blockIdx.y * 64, cb = blockIdx.x * 64;
    const int t = threadIdx.x;
    const int tr = t >> 4, tc4 = (t & 15) * 4;
    #pragma unroll
    for (int i = 0; i < 4; ++i) {
        const int r = i * 16 + tr;
        const float4 v = *(const float4*)&W[(size_t)(rb + r) * CC + cb + tc4];
        st[r][tc4 + 0] = v.x; st[r][tc4 + 1] = v.y;
        st[r][tc4 + 2] = v.z; st[r][tc4 + 3] = v.w;
    }
    __syncthreads();
    #pragma unroll
    for (int i = 0; i < 4; ++i) {
        const int c = i * 16 + tr;             // output row = original column
        bfu4 o;
        o[0] = f2bf(st[tc4 + 0][c]); o[1] = f2bf(st[tc4 + 1][c]);
        o[2] = f2bf(st[tc4 + 2][c]); o[3] = f2bf(st[tc4 + 3][c]);
        *(bfu4*)&out[(size_t)(cb + c) * CC + rb + tc4] = o;
    }
}

// ---------------------------------------------------------------------------
// RoPE tables: tab[t*32 + p] = (cos, sin) of t * theta^(-2p/64).
// ---------------------------------------------------------------------------
__global__ __launch_bounds__(256) void rope_tables(float2* __restrict__ tab)
{
    const int i = blockIdx.x * 256 + threadIdx.x;   // 65536 total
    const int t = i >> 5, p = i & 31;
    const float inv_freq = expf(-(float)(2 * p) * (9.210340371976184f / 64.0f));
    const float ang = (float)t * inv_freq;
    float s, c;
    sincosf(ang, &s, &c);
    tab[i] = make_float2(c, s);
}

// ---------------------------------------------------------------------------
// V [bh][t][d] bf16 -> Vt [bh][d][t] bf16. Coalesced both sides:
// per store instr, 256 consecutive t for one d.
// ---------------------------------------------------------------------------
__global__ __launch_bounds__(256) void transpose_v(
    const unsigned short* __restrict__ v, unsigned short* __restrict__ vt)
{
    const int bh = blockIdx.y;
    const int t  = blockIdx.x * 256 + threadIdx.x;
    const unsigned short* src = v + ((size_t)bh * TT + t) * DD;
    #pragma unroll
    for (int d0 = 0; d0 < 64; d0 += 8) {
        const bfu8 x = *(const bfu8*)(src + d0);
        #pragma unroll
        for (int j = 0; j < 8; ++j)
            vt[((size_t)bh * DD + d0 + j) * TT + t] = x[j];
    }
}

// ---------------------------------------------------------------------------
// MFMA GEMM, m97 structure (verified round 6). 128x128 tile, BK=32, 4 waves.
// ---------------------------------------------------------------------------
template<int MODE>
__global__ __launch_bounds__(256) void gemm_mfma(
    const unsigned short* __restrict__ A,
    const unsigned short* __restrict__ Wt,
    const float* __restrict__ bias,
    const float2* __restrict__ tab,
    void* __restrict__ outv)
{
    __shared__ short lds[128 * 32 * 2];        // A tile | B tile, 16 KiB
    short* As = lds;
    short* Bs = lds + 128 * 32;

    const int tid  = threadIdx.x;
    const int lane = tid & 63;
    const int w    = tid >> 6;                 // wave id 0..3
    const int wr   = w >> 1, wc = w & 1;       // 2x2 wave grid
    const int mb   = blockIdx.y * 128, nb = blockIdx.x * 128;
    const int z    = (MODE == 1) ? blockIdx.z : 0;
    const unsigned short* Bmat = Wt + (size_t)z * CC * CC;

    f32x4 acc[4][4] = {};

    for (int k0 = 0; k0 < CC; k0 += 32) {
        __syncthreads();                        // LDS safe to overwrite
        #pragma unroll
        for (int t2 = 0; t2 < 2; ++t2) {
            const int ci  = w * 128 + t2 * 64 + lane;   // chunk 0..511
            const int row = ci >> 2, kc = ci & 3;
            const unsigned short* ga = A    + (size_t)(mb + row) * CC + k0 + kc * 8;
            const unsigned short* gb = Bmat + (size_t)(nb + row) * CC + k0 + kc * 8;
            __builtin_amdgcn_global_load_lds(
                (const __attribute__((address_space(1))) unsigned int*)ga,
                (__attribute__((address_space(3))) unsigned int*)(As + (w * 2 + t2) * 512),
                16, 0, 0);
            __builtin_amdgcn_global_load_lds(
                (const __attribute__((address_space(1))) unsigned int*)gb,
                (__attribute__((address_space(3))) unsigned int*)(Bs + (w * 2 + t2) * 512),
                16, 0, 0);
        }
        __syncthreads();                        // staging data visible

        short8 a[4], b[4];
        #pragma unroll
        for (int i = 0; i < 4; ++i) {
            const int ro = (wr * 64 + i * 16 + (lane & 15)) * 32 + (lane >> 4) * 8;
            a[i] = *(const short8*)&As[ro];
            const int co = (wc * 64 + i * 16 + (lane & 15)) * 32 + (lane >> 4) * 8;
            b[i] = *(const short8*)&Bs[co];
        }
        #pragma unroll
        for (int i = 0; i < 4; ++i)
            #pragma unroll
            for (int j = 0; j < 4; ++j)
                acc[i][j] = __builtin_amdgcn_mfma_f32_16x16x32_bf16(
                    a[i], b[j], acc[i][j], 0, 0, 0);
    }

    // ---------------- epilogue ----------------
    if (MODE == 0) {
        float* out = (float*)outv;
        #pragma unroll
        for (int i = 0; i < 4; ++i) {
            const int m0 = mb + wr * 64 + i * 16 + (lane >> 4) * 4;
            #pragma unroll
            for (int j = 0; j < 4; ++j) {
                const int n = nb + wc * 64 + j * 16 + (lane & 15);
                const float bv = bias[n];
                #pragma unroll
                for (int r = 0; r < 4; ++r)
                    out[(size_t)(m0 + r) * CC + n] = acc[i][j][r] + bv;
            }
        }
    } else {
        unsigned short* dst = (unsigned short*)outv + (size_t)z * MM * CC;
        const bool do_rope = (z < 2);
        #pragma unroll
        for (int i = 0; i < 4; ++i) {
            const int m0 = mb + wr * 64 + i * 16 + (lane >> 4) * 4;
            #pragma unroll
            for (int j = 0; j < 4; ++j) {
                const int n = nb + wc * 64 + j * 16 + (lane & 15);
                const int h = n >> 6, d = n & 63;
                #pragma unroll
                for (int r = 0; r < 4; ++r) {
                    const int m  = m0 + r;
                    const int b_ = m >> 11, t = m & (TT - 1);
                    const float val     = acc[i][j][r];
                    const float partner = __shfl_xor(val, 1);
                    float r0, r1;
                    if (do_rope) {
                        const float2 cs = tab[t * 32 + (d >> 1)];
                        r0 = val * cs.x - partner * cs.y;
                        r1 = val * cs.y + partner * cs.x;
                    } else {
                        r0 = val; r1 = partner;
                    }
                    if ((lane & 1) == 0) {
                        const unsigned int pk =
                            (unsigned int)f2bf(r0) | ((unsigned int)f2bf(r1) << 16);
                        *(unsigned int*)&dst[(((size_t)(b_ * HH + h) * TT + t) * DD) + (d & ~1)] = pk;
                    }
                }
            }
        }
    }
}

// ---------------------------------------------------------------------------
// MFMA flash attention (causal). Block = one (b,h) x 64 q-rows; 4 waves x
// 16 q-rows. KV tiles of 64 keys in LDS, XOR-swizzled (G4: 128B rows).
// Fragment layouts identical to gemm_mfma (verified round 6):
//   a-frag: A[lane&15][ (lane>>4)*8+i ]      (16 rows x K32)
//   b-frag: B^T-form, read [n=lane&15][k]    (from row-major [n][k] tile)
//   C/D:    D[row=(lane>>4)*4+r][col=lane&15]
// QK^T: A=Q(16xD), B^T=K-tile [key][d].  PV: A=P(16x64), B^T=Vt-tile [d][key].
// Online softmax per q-row; row stats live in lanes sharing (lane>>4) group,
// reduced across the 16-lane (lane&15) axis via __shfl_xor.
// ---------------------------------------------------------------------------
__global__ __launch_bounds__(256) void attn_mfma(
    const unsigned short* __restrict__ qg, const unsigned short* __restrict__ kg,
    const unsigned short* __restrict__ vtg, unsigned short* __restrict__ att)
{
    __shared__ short Ks[64 * 64];      // [key][d], swizzled
    __shared__ short Vs[64 * 64];      // [d][key], swizzled
    __shared__ short Ps[4][16 * 64];   // per-wave [q][key], swizzled

    const int tid  = threadIdx.x;
    const int lane = tid & 63;
    const int w    = tid >> 6;
    const int l15  = lane & 15, l4 = lane >> 4;
    const int qt   = blockIdx.x;            // q tile 0..31
    const int bh   = blockIdx.y;            // 0..63
    const int qb   = qt * 64;
    const int b_   = bh >> 4, h = bh & 15;

    // Q a-fragments (rows qb + w*16 + l15, d = kc*32 + l4*8 .. +8)
    const unsigned short* qrow = qg + ((size_t)bh * TT + qb + w * 16 + l15) * DD;
    const short8 qf0 = *(const short8*)(qrow + l4 * 8);
    const short8 qf1 = *(const short8*)(qrow + 32 + l4 * 8);

    f32x4 acc_o[4] = {};                     // [dj]: O[q=l4*4+r][d=dj*16+l15]
    float m_run[4] = {-1e30f, -1e30f, -1e30f, -1e30f};
    float l_run[4] = {};

    const int srow = tid >> 2;               // staging row 0..63
    const int sc0  = (tid & 3) * 16;         // staging col base

    const int ntile = qt + 1;
    for (int kt = 0; kt < ntile; ++kt) {
        const int kb = kt * 64;
        __syncthreads();                     // prior tile's LDS reads done
        #pragma unroll
        for (int half = 0; half < 2; ++half) {
            const int c0 = sc0 + half * 8;
            const short8 kv = *(const short8*)(kg  + ((size_t)bh * TT + kb + srow) * DD + c0);
            const short8 vv = *(const short8*)(vtg + ((size_t)bh * DD + srow) * TT + kb + c0);
            const int bo = (srow * 128 + c0 * 2) ^ ((srow & 7) << 4);
            *(short8*)((char*)Ks + bo) = kv;
            *(short8*)((char*)Vs + bo) = vv;
        }
        __syncthreads();                     // tile visible

        // ---- QK^T: S[16 q][64 key] ----
        f32x4 s4[4];
        #pragma unroll
        for (int kj = 0; kj < 4; ++kj) {
            const int key = kj * 16 + l15;
            const short8 kf0 = *(const short8*)((char*)Ks + ((key * 128 +      l4 * 16) ^ ((key & 7) << 4)));
            const short8 kf1 = *(const short8*)((char*)Ks + ((key * 128 + 64 + l4 * 16) ^ ((key & 7) << 4)));
            f32x4 zz = {};
            zz = __builtin_amdgcn_mfma_f32_16x16x32_bf16(qf0, kf0, zz, 0, 0, 0);
            zz = __builtin_amdgcn_mfma_f32_16x16x32_bf16(qf1, kf1, zz, 0, 0, 0);
            s4[kj] = zz;
        }

        // ---- scale + causal mask + tile max ----
        float p[4][4];                        // [kj][r]
        float tmax[4] = {-1e30f, -1e30f, -1e30f, -1e30f};
        const bool diag = (kt == ntile - 1);
        #pragma unroll
        for (int kj = 0; kj < 4; ++kj)
            #pragma unroll
            for (int r = 0; r < 4; ++r) {
                float s = s4[kj][r] * 0.125f;
                if (diag) {
                    const int key_g = kb + kj * 16 + l15;
                    const int q_g   = qb + w * 16 + l4 * 4 + r;
                    if (key_g > q_g) s = -1e30f;
                }
                p[kj][r] = s;
                tmax[r] = fmaxf(tmax[r], s);
            }
        #pragma unroll
        for (int mk = 1; mk < 16; mk <<= 1)
            #pragma unroll
            for (int r = 0; r < 4; ++r)
                tmax[r] = fmaxf(tmax[r], __shfl_xor(tmax[r], mk));

        // ---- online softmax update ----
        #pragma unroll
        for (int r = 0; r < 4; ++r) {
            const float mn   = fmaxf(m_run[r], tmax[r]);
            const float corr = __expf(m_run[r] - mn);
            m_run[r] = mn;
            l_run[r] *= corr;
            #pragma unroll
            for (int dj = 0; dj < 4; ++dj) acc_o[dj][r] *= corr;
            float ls = 0.f;
            #pragma unroll
            for (int kj = 0; kj < 4; ++kj) {
                const float e = __expf(p[kj][r] - mn);
                p[kj][r] = e;
                ls += e;
            }
            l_run[r] += ls;                  // lane-partial; reduced at end
        }

        // ---- P -> LDS (bf16, A-frag layout source) ----
        #pragma unroll
        for (int kj = 0; kj < 4; ++kj)
            #pragma unroll
            for (int r = 0; r < 4; ++r) {
                const int qr  = l4 * 4 + r;
                const int key = kj * 16 + l15;
                const int bo  = (qr * 128 + key * 2) ^ ((qr & 7) << 4);
                *(short*)((char*)&Ps[w][0] + bo) = (short)f2bf(p[kj][r]);
            }

        // ---- PV: O += P (16x64) . V (64x64) ----
        const short8 pa0 = *(const short8*)((char*)&Ps[w][0] + ((l15 * 128 +      l4 * 16) ^ ((l15 & 7) << 4)));
        const short8 pa1 = *(const short8*)((char*)&Ps[w][0] + ((l15 * 128 + 64 + l4 * 16) ^ ((l15 & 7) << 4)));
        #pragma unroll
        for (int dj = 0; dj < 4; ++dj) {
            const int dr = dj * 16 + l15;
            const short8 vf0 = *(const short8*)((char*)Vs + ((dr * 128 +      l4 * 16) ^ ((dr & 7) << 4)));
            const short8 vf1 = *(const short8*)((char*)Vs + ((dr * 128 + 64 + l4 * 16) ^ ((dr & 7) << 4)));
            acc_o[dj] = __builtin_amdgcn_mfma_f32_16x16x32_bf16(pa0, vf0, acc_o[dj], 0, 0, 0);
            acc_o[dj] = __builtin_amdgcn_mfma_f32_16x16x32_bf16(pa1, vf1, acc_o[dj], 0, 0, 0);
        }
    }

    // ---- finalize: reduce l across the 16-lane axis, normalize, store ----
    #pragma unroll
    for (int mk = 1; mk < 16; mk <<= 1)
        #pragma unroll
        for (int r = 0; r < 4; ++r)
            l_run[r] += __shfl_xor(l_run[r], mk);

    #pragma unroll
    for (int r = 0; r < 4; ++r) {
        const float inv = 1.0f / l_run[r];
        const int t = qb + w * 16 + l4 * 4 + r;
        unsigned short* orow = att + ((size_t)(b_ * TT + t)) * CC + h * DD;
        #pragma unroll
        for (int dj = 0; dj < 4; ++dj)
            orow[dj * 16 + l15] = f2bf(acc_o[dj][r] * inv);
    }
}

// ---------------------------------------------------------------------------
extern "C" void kernel_launch(void* const* d_in, const int* in_sizes, int n_in,
                              void* d_out, int out_size, void* d_ws, size_t ws_size,
                              hipStream_t stream) {
    const float* x  = (const float*)d_in[0];
    const float* Wq = (const float*)d_in[1];
    const float* Wk = (const float*)d_in[2];
    const float* Wv = (const float*)d_in[3];
    const float* Wo = (const float*)d_in[4];
    const float* bo = (const float*)d_in[5];
    float* out = (float*)d_out;

    char* ws = (char*)d_ws;
    unsigned short* xb  = (unsigned short*)ws;                        // 16 MB (dead after QKV GEMM)
    unsigned short* aw  = xb;                                         // aliases xb (attn out)
    unsigned short* wt  = (unsigned short*)(ws + (16ull << 20));      //  8 MB (4x [N][K] bf16)
    unsigned short* qkv = (unsigned short*)(ws + (24ull << 20));      // 48 MB (q|k|v, [B][H][T][D])
    unsigned short* vt  = (unsigned short*)(ws + (72ull << 20));      // 16 MB ([bh][d][T])
    float2*         tab = (float2*)       (ws + (88ull << 20));       // 512 KB

    convert_x  <<<4096, 256, 0, stream>>>(x, xb);
    transpose_w<<<dim3(16, 16, 4), 256, 0, stream>>>(Wq, Wk, Wv, Wo, wt);
    rope_tables<<<256, 256, 0, stream>>>(tab);

    gemm_mfma<1><<<dim3(8, 64, 3), 256, 0, stream>>>(xb, wt, nullptr, tab, qkv);

    const size_t NEL = (size_t)MM * CC;
    transpose_v<<<dim3(8, 64), 256, 0, stream>>>(qkv + 2 * NEL, vt);

    attn_mfma<<<dim3(32, 64), 256, 0, stream>>>(qkv, qkv + NEL, vt, aw);

    gemm_mfma<0><<<dim3(8, 64), 256, 0, stream>>>(
        aw, wt + 3ull * CC * CC, bo, tab, out);
}

// Round 12
// 426.168 us; speedup vs baseline: 3.3362x; 1.0895x over previous
//
#include <hip/hip_runtime.h>
#include <math.h>

#define HH 16
#define DD 64
#define TT 2048
#define BB 4
#define CC 1024
#define MM (BB*TT)   // 8192

typedef __attribute__((ext_vector_type(8))) short short8;     // 8 bf16 (4 VGPRs)
typedef __attribute__((ext_vector_type(4))) float f32x4;      // MFMA C/D
typedef __attribute__((ext_vector_type(8))) unsigned short bfu8;
typedef __attribute__((ext_vector_type(4))) unsigned short bfu4;

__device__ __forceinline__ unsigned short f2bf(float f) {
    unsigned int u = __builtin_bit_cast(unsigned int, f);
    unsigned int r = (u + 0x7fffu + ((u >> 16) & 1u)) >> 16;   // RNE
    return (unsigned short)r;
}
__device__ __forceinline__ float bf2f(unsigned short s) {
    unsigned int u = ((unsigned int)s) << 16;
    return __builtin_bit_cast(float, u);
}

// ---------------------------------------------------------------------------
// x fp32 [M][C] -> bf16 same layout. 8 elems/thread.
// ---------------------------------------------------------------------------
__global__ __launch_bounds__(256) void convert_x(
    const float* __restrict__ x, unsigned short* __restrict__ xb)
{
    const size_t i = (size_t)blockIdx.x * 256 + threadIdx.x;
    const float4 a = ((const float4*)x)[i * 2];
    const float4 b = ((const float4*)x)[i * 2 + 1];
    bfu8 o;
    o[0] = f2bf(a.x); o[1] = f2bf(a.y); o[2] = f2bf(a.z); o[3] = f2bf(a.w);
    o[4] = f2bf(b.x); o[5] = f2bf(b.y); o[6] = f2bf(b.z); o[7] = f2bf(b.w);
    *(bfu8*)(xb + i * 8) = o;
}

// ---------------------------------------------------------------------------
// W [K][N] fp32 -> Wt [N][K] bf16 (transposed), z selects one of 4 matrices.
// ---------------------------------------------------------------------------
__global__ __launch_bounds__(256) void transpose_w(
    const float* __restrict__ Wq, const float* __restrict__ Wk,
    const float* __restrict__ Wv, const float* __restrict__ Wo,
    unsigned short* __restrict__ Wt)
{
    __shared__ float st[64][65];
    const int z = blockIdx.z;
    const float* W = (z == 0) ? Wq : (z == 1) ? Wk : (z == 2) ? Wv : Wo;
    unsigned short* out = Wt + (size_t)z * CC * CC;
    const int rb = blockIdx.y * 64, cb = blockIdx.x * 64;
    const int t = threadIdx.x;
    const int tr = t >> 4, tc4 = (t & 15) * 4;
    #pragma unroll
    for (int i = 0; i < 4; ++i) {
        const int r = i * 16 + tr;
        const float4 v = *(const float4*)&W[(size_t)(rb + r) * CC + cb + tc4];
        st[r][tc4 + 0] = v.x; st[r][tc4 + 1] = v.y;
        st[r][tc4 + 2] = v.z; st[r][tc4 + 3] = v.w;
    }
    __syncthreads();
    #pragma unroll
    for (int i = 0; i < 4; ++i) {
        const int c = i * 16 + tr;             // output row = original column
        bfu4 o;
        o[0] = f2bf(st[tc4 + 0][c]); o[1] = f2bf(st[tc4 + 1][c]);
        o[2] = f2bf(st[tc4 + 2][c]); o[3] = f2bf(st[tc4 + 3][c]);
        *(bfu4*)&out[(size_t)(cb + c) * CC + rb + tc4] = o;
    }
}

// ---------------------------------------------------------------------------
// RoPE tables: tab[t*32 + p] = (cos, sin) of t * theta^(-2p/64).
// ---------------------------------------------------------------------------
__global__ __launch_bounds__(256) void rope_tables(float2* __restrict__ tab)
{
    const int i = blockIdx.x * 256 + threadIdx.x;   // 65536 total
    const int t = i >> 5, p = i & 31;
    const float inv_freq = expf(-(float)(2 * p) * (9.210340371976184f / 64.0f));
    const float ang = (float)t * inv_freq;
    float s, c;
    sincosf(ang, &s, &c);
    tab[i] = make_float2(c, s);
}

// ---------------------------------------------------------------------------
// V [bh][t][d] bf16 -> Vt [bh][d][t] bf16.
// ---------------------------------------------------------------------------
__global__ __launch_bounds__(256) void transpose_v(
    const unsigned short* __restrict__ v, unsigned short* __restrict__ vt)
{
    const int bh = blockIdx.y;
    const int t  = blockIdx.x * 256 + threadIdx.x;
    const unsigned short* src = v + ((size_t)bh * TT + t) * DD;
    #pragma unroll
    for (int d0 = 0; d0 < 64; d0 += 8) {
        const bfu8 x = *(const bfu8*)(src + d0);
        #pragma unroll
        for (int j = 0; j < 8; ++j)
            vt[((size_t)bh * DD + d0 + j) * TT + t] = x[j];
    }
}

// ---------------------------------------------------------------------------
// MFMA GEMM, m97 structure (verified round 6). 128x128 tile, BK=32, 4 waves.
// ---------------------------------------------------------------------------
template<int MODE>
__global__ __launch_bounds__(256) void gemm_mfma(
    const unsigned short* __restrict__ A,
    const unsigned short* __restrict__ Wt,
    const float* __restrict__ bias,
    const float2* __restrict__ tab,
    void* __restrict__ outv)
{
    __shared__ short lds[128 * 32 * 2];        // A tile | B tile, 16 KiB
    short* As = lds;
    short* Bs = lds + 128 * 32;

    const int tid  = threadIdx.x;
    const int lane = tid & 63;
    const int w    = tid >> 6;                 // wave id 0..3
    const int wr   = w >> 1, wc = w & 1;       // 2x2 wave grid
    const int mb   = blockIdx.y * 128, nb = blockIdx.x * 128;
    const int z    = (MODE == 1) ? blockIdx.z : 0;
    const unsigned short* Bmat = Wt + (size_t)z * CC * CC;

    f32x4 acc[4][4] = {};

    for (int k0 = 0; k0 < CC; k0 += 32) {
        __syncthreads();                        // LDS safe to overwrite
        #pragma unroll
        for (int t2 = 0; t2 < 2; ++t2) {
            const int ci  = w * 128 + t2 * 64 + lane;   // chunk 0..511
            const int row = ci >> 2, kc = ci & 3;
            const unsigned short* ga = A    + (size_t)(mb + row) * CC + k0 + kc * 8;
            const unsigned short* gb = Bmat + (size_t)(nb + row) * CC + k0 + kc * 8;
            __builtin_amdgcn_global_load_lds(
                (const __attribute__((address_space(1))) unsigned int*)ga,
                (__attribute__((address_space(3))) unsigned int*)(As + (w * 2 + t2) * 512),
                16, 0, 0);
            __builtin_amdgcn_global_load_lds(
                (const __attribute__((address_space(1))) unsigned int*)gb,
                (__attribute__((address_space(3))) unsigned int*)(Bs + (w * 2 + t2) * 512),
                16, 0, 0);
        }
        __syncthreads();                        // staging data visible

        short8 a[4], b[4];
        #pragma unroll
        for (int i = 0; i < 4; ++i) {
            const int ro = (wr * 64 + i * 16 + (lane & 15)) * 32 + (lane >> 4) * 8;
            a[i] = *(const short8*)&As[ro];
            const int co = (wc * 64 + i * 16 + (lane & 15)) * 32 + (lane >> 4) * 8;
            b[i] = *(const short8*)&Bs[co];
        }
        #pragma unroll
        for (int i = 0; i < 4; ++i)
            #pragma unroll
            for (int j = 0; j < 4; ++j)
                acc[i][j] = __builtin_amdgcn_mfma_f32_16x16x32_bf16(
                    a[i], b[j], acc[i][j], 0, 0, 0);
    }

    // ---------------- epilogue ----------------
    if (MODE == 0) {
        float* out = (float*)outv;
        #pragma unroll
        for (int i = 0; i < 4; ++i) {
            const int m0 = mb + wr * 64 + i * 16 + (lane >> 4) * 4;
            #pragma unroll
            for (int j = 0; j < 4; ++j) {
                const int n = nb + wc * 64 + j * 16 + (lane & 15);
                const float bv = bias[n];
                #pragma unroll
                for (int r = 0; r < 4; ++r)
                    out[(size_t)(m0 + r) * CC + n] = acc[i][j][r] + bv;
            }
        }
    } else {
        unsigned short* dst = (unsigned short*)outv + (size_t)z * MM * CC;
        const bool do_rope = (z < 2);
        #pragma unroll
        for (int i = 0; i < 4; ++i) {
            const int m0 = mb + wr * 64 + i * 16 + (lane >> 4) * 4;
            #pragma unroll
            for (int j = 0; j < 4; ++j) {
                const int n = nb + wc * 64 + j * 16 + (lane & 15);
                const int h = n >> 6, d = n & 63;
                #pragma unroll
                for (int r = 0; r < 4; ++r) {
                    const int m  = m0 + r;
                    const int b_ = m >> 11, t = m & (TT - 1);
                    const float val     = acc[i][j][r];
                    const float partner = __shfl_xor(val, 1);
                    float r0, r1;
                    if (do_rope) {
                        const float2 cs = tab[t * 32 + (d >> 1)];
                        r0 = val * cs.x - partner * cs.y;
                        r1 = val * cs.y + partner * cs.x;
                    } else {
                        r0 = val; r1 = partner;
                    }
                    if ((lane & 1) == 0) {
                        const unsigned int pk =
                            (unsigned int)f2bf(r0) | ((unsigned int)f2bf(r1) << 16);
                        *(unsigned int*)&dst[(((size_t)(b_ * HH + h) * TT + t) * DD) + (d & ~1)] = pk;
                    }
                }
            }
        }
    }
}

// ---------------------------------------------------------------------------
// MFMA flash attention (causal), round-10: double-buffered K/V LDS with
// register prefetch (stage loads issued BEFORE compute, LDS write after),
// one barrier per tile, reversed qt dispatch (long blocks first), setprio
// around MFMA clusters. Compute core identical to round-9 (HW-verified).
// ---------------------------------------------------------------------------
__global__ __launch_bounds__(256) void attn_mfma(
    const unsigned short* __restrict__ qg, const unsigned short* __restrict__ kg,
    const unsigned short* __restrict__ vtg, unsigned short* __restrict__ att)
{
    __shared__ short Ks[2][64 * 64];   // [key][d], swizzled
    __shared__ short Vs[2][64 * 64];   // [d][key], swizzled
    __shared__ short Ps[4][16 * 64];   // per-wave [q][key], swizzled

    const int tid  = threadIdx.x;
    const int lane = tid & 63;
    const int w    = tid >> 6;
    const int l15  = lane & 15, l4 = lane >> 4;
    const int qt   = 31 - blockIdx.x;       // reversed: 32-tile blocks first
    const int bh   = blockIdx.y;            // 0..63
    const int qb   = qt * 64;
    const int b_   = bh >> 4, h = bh & 15;

    const unsigned short* qrow = qg + ((size_t)bh * TT + qb + w * 16 + l15) * DD;
    const short8 qf0 = *(const short8*)(qrow + l4 * 8);
    const short8 qf1 = *(const short8*)(qrow + 32 + l4 * 8);

    f32x4 acc_o[4] = {};                     // [dj]: O[q=l4*4+r][d=dj*16+l15]
    float m_run[4] = {-1e30f, -1e30f, -1e30f, -1e30f};
    float l_run[4] = {};

    const int srow = tid >> 2;               // staging row 0..63
    const int sc0  = (tid & 3) * 16;         // staging col base
    const int bo0  = (srow * 128 + sc0 * 2)       ^ ((srow & 7) << 4);
    const int bo1  = (srow * 128 + (sc0 + 8) * 2) ^ ((srow & 7) << 4);
    const unsigned short* kst = kg  + ((size_t)bh * TT + srow) * DD + sc0;  // +kb*DD
    const unsigned short* vst = vtg + ((size_t)bh * DD + srow) * TT + sc0;  // +kb

    const int ntile = qt + 1;

    // stage tile 0 directly
    {
        const short8 k0 = *(const short8*)(kst);
        const short8 k1 = *(const short8*)(kst + 8);
        const short8 v0 = *(const short8*)(vst);
        const short8 v1 = *(const short8*)(vst + 8);
        *(short8*)((char*)&Ks[0][0] + bo0) = k0;
        *(short8*)((char*)&Ks[0][0] + bo1) = k1;
        *(short8*)((char*)&Vs[0][0] + bo0) = v0;
        *(short8*)((char*)&Vs[0][0] + bo1) = v1;
    }
    __syncthreads();

    for (int kt = 0; kt < ntile; ++kt) {
        const int kb  = kt * 64;
        const int cur = kt & 1;
        const short* Kc = &Ks[cur][0];
        const short* Vc = &Vs[cur][0];

        // ---- issue next-tile loads (latency hides under compute) ----
        short8 nk0, nk1, nv0, nv1;
        const bool has_next = (kt + 1 < ntile);
        if (has_next) {
            const size_t ko = (size_t)(kb + 64) * DD;
            nk0 = *(const short8*)(kst + ko);
            nk1 = *(const short8*)(kst + ko + 8);
            nv0 = *(const short8*)(vst + kb + 64);
            nv1 = *(const short8*)(vst + kb + 64 + 8);
        }

        // ---- QK^T: S[16 q][64 key] ----
        f32x4 s4[4];
        __builtin_amdgcn_s_setprio(1);
        #pragma unroll
        for (int kj = 0; kj < 4; ++kj) {
            const int key = kj * 16 + l15;
            const short8 kf0 = *(const short8*)((char*)Kc + ((key * 128 +      l4 * 16) ^ ((key & 7) << 4)));
            const short8 kf1 = *(const short8*)((char*)Kc + ((key * 128 + 64 + l4 * 16) ^ ((key & 7) << 4)));
            f32x4 zz = {};
            zz = __builtin_amdgcn_mfma_f32_16x16x32_bf16(qf0, kf0, zz, 0, 0, 0);
            zz = __builtin_amdgcn_mfma_f32_16x16x32_bf16(qf1, kf1, zz, 0, 0, 0);
            s4[kj] = zz;
        }
        __builtin_amdgcn_s_setprio(0);

        // ---- scale + causal mask + tile max ----
        float p[4][4];                        // [kj][r]
        float tmax[4] = {-1e30f, -1e30f, -1e30f, -1e30f};
        const bool diag = (kt == ntile - 1);
        #pragma unroll
        for (int kj = 0; kj < 4; ++kj)
            #pragma unroll
            for (int r = 0; r < 4; ++r) {
                float s = s4[kj][r] * 0.125f;
                if (diag) {
                    const int key_g = kb + kj * 16 + l15;
                    const int q_g   = qb + w * 16 + l4 * 4 + r;
                    if (key_g > q_g) s = -1e30f;
                }
                p[kj][r] = s;
                tmax[r] = fmaxf(tmax[r], s);
            }
        #pragma unroll
        for (int mk = 1; mk < 16; mk <<= 1)
            #pragma unroll
            for (int r = 0; r < 4; ++r)
                tmax[r] = fmaxf(tmax[r], __shfl_xor(tmax[r], mk));

        // ---- online softmax update ----
        #pragma unroll
        for (int r = 0; r < 4; ++r) {
            const float mn   = fmaxf(m_run[r], tmax[r]);
            const float corr = __expf(m_run[r] - mn);
            m_run[r] = mn;
            l_run[r] *= corr;
            #pragma unroll
            for (int dj = 0; dj < 4; ++dj) acc_o[dj][r] *= corr;
            float ls = 0.f;
            #pragma unroll
            for (int kj = 0; kj < 4; ++kj) {
                const float e = __expf(p[kj][r] - mn);
                p[kj][r] = e;
                ls += e;
            }
            l_run[r] += ls;                  // lane-partial; reduced at end
        }

        // ---- P -> LDS (bf16, A-frag layout source) ----
        #pragma unroll
        for (int kj = 0; kj < 4; ++kj)
            #pragma unroll
            for (int r = 0; r < 4; ++r) {
                const int qr  = l4 * 4 + r;
                const int key = kj * 16 + l15;
                const int bo  = (qr * 128 + key * 2) ^ ((qr & 7) << 4);
                *(short*)((char*)&Ps[w][0] + bo) = (short)f2bf(p[kj][r]);
            }

        // ---- PV: O += P (16x64) . V (64x64) ----
        const short8 pa0 = *(const short8*)((char*)&Ps[w][0] + ((l15 * 128 +      l4 * 16) ^ ((l15 & 7) << 4)));
        const short8 pa1 = *(const short8*)((char*)&Ps[w][0] + ((l15 * 128 + 64 + l4 * 16) ^ ((l15 & 7) << 4)));
        __builtin_amdgcn_s_setprio(1);
        #pragma unroll
        for (int dj = 0; dj < 4; ++dj) {
            const int dr = dj * 16 + l15;
            const short8 vf0 = *(const short8*)((char*)Vc + ((dr * 128 +      l4 * 16) ^ ((dr & 7) << 4)));
            const short8 vf1 = *(const short8*)((char*)Vc + ((dr * 128 + 64 + l4 * 16) ^ ((dr & 7) << 4)));
            acc_o[dj] = __builtin_amdgcn_mfma_f32_16x16x32_bf16(pa0, vf0, acc_o[dj], 0, 0, 0);
            acc_o[dj] = __builtin_amdgcn_mfma_f32_16x16x32_bf16(pa1, vf1, acc_o[dj], 0, 0, 0);
        }
        __builtin_amdgcn_s_setprio(0);

        // ---- write prefetched tile into the other buffer ----
        if (has_next) {
            char* Kn = (char*)&Ks[cur ^ 1][0];
            char* Vn = (char*)&Vs[cur ^ 1][0];
            *(short8*)(Kn + bo0) = nk0;
            *(short8*)(Kn + bo1) = nk1;
            *(short8*)(Vn + bo0) = nv0;
            *(short8*)(Vn + bo1) = nv1;
        }
        __syncthreads();                     // next buffer visible; cur reusable
    }

    // ---- finalize: reduce l across the 16-lane axis, normalize, store ----
    #pragma unroll
    for (int mk = 1; mk < 16; mk <<= 1)
        #pragma unroll
        for (int r = 0; r < 4; ++r)
            l_run[r] += __shfl_xor(l_run[r], mk);

    #pragma unroll
    for (int r = 0; r < 4; ++r) {
        const float inv = 1.0f / l_run[r];
        const int t = qb + w * 16 + l4 * 4 + r;
        unsigned short* orow = att + ((size_t)(b_ * TT + t)) * CC + h * DD;
        #pragma unroll
        for (int dj = 0; dj < 4; ++dj)
            orow[dj * 16 + l15] = f2bf(acc_o[dj][r] * inv);
    }
}

// ---------------------------------------------------------------------------
extern "C" void kernel_launch(void* const* d_in, const int* in_sizes, int n_in,
                              void* d_out, int out_size, void* d_ws, size_t ws_size,
                              hipStream_t stream) {
    const float* x  = (const float*)d_in[0];
    const float* Wq = (const float*)d_in[1];
    const float* Wk = (const float*)d_in[2];
    const float* Wv = (const float*)d_in[3];
    const float* Wo = (const float*)d_in[4];
    const float* bo = (const float*)d_in[5];
    float* out = (float*)d_out;

    char* ws = (char*)d_ws;
    unsigned short* xb  = (unsigned short*)ws;                        // 16 MB (dead after QKV GEMM)
    unsigned short* aw  = xb;                                         // aliases xb (attn out)
    unsigned short* wt  = (unsigned short*)(ws + (16ull << 20));      //  8 MB (4x [N][K] bf16)
    unsigned short* qkv = (unsigned short*)(ws + (24ull << 20));      // 48 MB (q|k|v, [B][H][T][D])
    unsigned short* vt  = (unsigned short*)(ws + (72ull << 20));      // 16 MB ([bh][d][T])
    float2*         tab = (float2*)       (ws + (88ull << 20));       // 512 KB

    convert_x  <<<4096, 256, 0, stream>>>(x, xb);
    transpose_w<<<dim3(16, 16, 4), 256, 0, stream>>>(Wq, Wk, Wv, Wo, wt);
    rope_tables<<<256, 256, 0, stream>>>(tab);

    gemm_mfma<1><<<dim3(8, 64, 3), 256, 0, stream>>>(xb, wt, nullptr, tab, qkv);

    const size_t NEL = (size_t)MM * CC;
    transpose_v<<<dim3(8, 64), 256, 0, stream>>>(qkv + 2 * NEL, vt);

    attn_mfma<<<dim3(32, 64), 256, 0, stream>>>(qkv, qkv + NEL, vt, aw);

    gemm_mfma<0><<<dim3(8, 64), 256, 0, stream>>>(
        aw, wt + 3ull * CC * CC, bo, tab, out);
}

// Round 13
// 409.375 us; speedup vs baseline: 3.4730x; 1.0410x over previous
//
#include <hip/hip_runtime.h>
#include <math.h>

#define HH 16
#define DD 64
#define TT 2048
#define BB 4
#define CC 1024
#define MM (BB*TT)   // 8192

typedef __attribute__((ext_vector_type(8))) short short8;     // 8 bf16 (4 VGPRs)
typedef __attribute__((ext_vector_type(4))) float f32x4;      // MFMA C/D
typedef __attribute__((ext_vector_type(8))) unsigned short bfu8;
typedef __attribute__((ext_vector_type(4))) unsigned short bfu4;

__device__ __forceinline__ unsigned short f2bf(float f) {
    unsigned int u = __builtin_bit_cast(unsigned int, f);
    unsigned int r = (u + 0x7fffu + ((u >> 16) & 1u)) >> 16;   // RNE
    return (unsigned short)r;
}
__device__ __forceinline__ float bf2f(unsigned short s) {
    unsigned int u = ((unsigned int)s) << 16;
    return __builtin_bit_cast(float, u);
}

// ---------------------------------------------------------------------------
// x fp32 [M][C] -> bf16 same layout. 8 elems/thread.
// ---------------------------------------------------------------------------
__global__ __launch_bounds__(256) void convert_x(
    const float* __restrict__ x, unsigned short* __restrict__ xb)
{
    const size_t i = (size_t)blockIdx.x * 256 + threadIdx.x;
    const float4 a = ((const float4*)x)[i * 2];
    const float4 b = ((const float4*)x)[i * 2 + 1];
    bfu8 o;
    o[0] = f2bf(a.x); o[1] = f2bf(a.y); o[2] = f2bf(a.z); o[3] = f2bf(a.w);
    o[4] = f2bf(b.x); o[5] = f2bf(b.y); o[6] = f2bf(b.z); o[7] = f2bf(b.w);
    *(bfu8*)(xb + i * 8) = o;
}

// ---------------------------------------------------------------------------
// W [K][N] fp32 -> Wt [N][K] bf16 (transposed), z selects one of 4 matrices.
// ---------------------------------------------------------------------------
__global__ __launch_bounds__(256) void transpose_w(
    const float* __restrict__ Wq, const float* __restrict__ Wk,
    const float* __restrict__ Wv, const float* __restrict__ Wo,
    unsigned short* __restrict__ Wt)
{
    __shared__ float st[64][65];
    const int z = blockIdx.z;
    const float* W = (z == 0) ? Wq : (z == 1) ? Wk : (z == 2) ? Wv : Wo;
    unsigned short* out = Wt + (size_t)z * CC * CC;
    const int rb = blockIdx.y * 64, cb = blockIdx.x * 64;
    const int t = threadIdx.x;
    const int tr = t >> 4, tc4 = (t & 15) * 4;
    #pragma unroll
    for (int i = 0; i < 4; ++i) {
        const int r = i * 16 + tr;
        const float4 v = *(const float4*)&W[(size_t)(rb + r) * CC + cb + tc4];
        st[r][tc4 + 0] = v.x; st[r][tc4 + 1] = v.y;
        st[r][tc4 + 2] = v.z; st[r][tc4 + 3] = v.w;
    }
    __syncthreads();
    #pragma unroll
    for (int i = 0; i < 4; ++i) {
        const int c = i * 16 + tr;             // output row = original column
        bfu4 o;
        o[0] = f2bf(st[tc4 + 0][c]); o[1] = f2bf(st[tc4 + 1][c]);
        o[2] = f2bf(st[tc4 + 2][c]); o[3] = f2bf(st[tc4 + 3][c]);
        *(bfu4*)&out[(size_t)(cb + c) * CC + rb + tc4] = o;
    }
}

// ---------------------------------------------------------------------------
// RoPE tables: tab[t*32 + p] = (cos, sin) of t * theta^(-2p/64).
// ---------------------------------------------------------------------------
__global__ __launch_bounds__(256) void rope_tables(float2* __restrict__ tab)
{
    const int i = blockIdx.x * 256 + threadIdx.x;   // 65536 total
    const int t = i >> 5, p = i & 31;
    const float inv_freq = expf(-(float)(2 * p) * (9.210340371976184f / 64.0f));
    const float ang = (float)t * inv_freq;
    float s, c;
    sincosf(ang, &s, &c);
    tab[i] = make_float2(c, s);
}

// ---------------------------------------------------------------------------
// V [bh][t][d] bf16 -> Vt [bh][d][t] bf16.
// ---------------------------------------------------------------------------
__global__ __launch_bounds__(256) void transpose_v(
    const unsigned short* __restrict__ v, unsigned short* __restrict__ vt)
{
    const int bh = blockIdx.y;
    const int t  = blockIdx.x * 256 + threadIdx.x;
    const unsigned short* src = v + ((size_t)bh * TT + t) * DD;
    #pragma unroll
    for (int d0 = 0; d0 < 64; d0 += 8) {
        const bfu8 x = *(const bfu8*)(src + d0);
        #pragma unroll
        for (int j = 0; j < 8; ++j)
            vt[((size_t)bh * DD + d0 + j) * TT + t] = x[j];
    }
}

// ---------------------------------------------------------------------------
// MFMA GEMM, m97 structure (verified round 6). 128x128 tile, BK=32, 4 waves.
// z==0 (Q): output pre-scaled by D^-0.5 = 0.125 (folded out of attention).
// ---------------------------------------------------------------------------
template<int MODE>
__global__ __launch_bounds__(256) void gemm_mfma(
    const unsigned short* __restrict__ A,
    const unsigned short* __restrict__ Wt,
    const float* __restrict__ bias,
    const float2* __restrict__ tab,
    void* __restrict__ outv)
{
    __shared__ short lds[128 * 32 * 2];        // A tile | B tile, 16 KiB
    short* As = lds;
    short* Bs = lds + 128 * 32;

    const int tid  = threadIdx.x;
    const int lane = tid & 63;
    const int w    = tid >> 6;                 // wave id 0..3
    const int wr   = w >> 1, wc = w & 1;       // 2x2 wave grid
    const int mb   = blockIdx.y * 128, nb = blockIdx.x * 128;
    const int z    = (MODE == 1) ? blockIdx.z : 0;
    const unsigned short* Bmat = Wt + (size_t)z * CC * CC;

    f32x4 acc[4][4] = {};

    for (int k0 = 0; k0 < CC; k0 += 32) {
        __syncthreads();                        // LDS safe to overwrite
        #pragma unroll
        for (int t2 = 0; t2 < 2; ++t2) {
            const int ci  = w * 128 + t2 * 64 + lane;   // chunk 0..511
            const int row = ci >> 2, kc = ci & 3;
            const unsigned short* ga = A    + (size_t)(mb + row) * CC + k0 + kc * 8;
            const unsigned short* gb = Bmat + (size_t)(nb + row) * CC + k0 + kc * 8;
            __builtin_amdgcn_global_load_lds(
                (const __attribute__((address_space(1))) unsigned int*)ga,
                (__attribute__((address_space(3))) unsigned int*)(As + (w * 2 + t2) * 512),
                16, 0, 0);
            __builtin_amdgcn_global_load_lds(
                (const __attribute__((address_space(1))) unsigned int*)gb,
                (__attribute__((address_space(3))) unsigned int*)(Bs + (w * 2 + t2) * 512),
                16, 0, 0);
        }
        __syncthreads();                        // staging data visible

        short8 a[4], b[4];
        #pragma unroll
        for (int i = 0; i < 4; ++i) {
            const int ro = (wr * 64 + i * 16 + (lane & 15)) * 32 + (lane >> 4) * 8;
            a[i] = *(const short8*)&As[ro];
            const int co = (wc * 64 + i * 16 + (lane & 15)) * 32 + (lane >> 4) * 8;
            b[i] = *(const short8*)&Bs[co];
        }
        #pragma unroll
        for (int i = 0; i < 4; ++i)
            #pragma unroll
            for (int j = 0; j < 4; ++j)
                acc[i][j] = __builtin_amdgcn_mfma_f32_16x16x32_bf16(
                    a[i], b[j], acc[i][j], 0, 0, 0);
    }

    // ---------------- epilogue ----------------
    if (MODE == 0) {
        float* out = (float*)outv;
        #pragma unroll
        for (int i = 0; i < 4; ++i) {
            const int m0 = mb + wr * 64 + i * 16 + (lane >> 4) * 4;
            #pragma unroll
            for (int j = 0; j < 4; ++j) {
                const int n = nb + wc * 64 + j * 16 + (lane & 15);
                const float bv = bias[n];
                #pragma unroll
                for (int r = 0; r < 4; ++r)
                    out[(size_t)(m0 + r) * CC + n] = acc[i][j][r] + bv;
            }
        }
    } else {
        unsigned short* dst = (unsigned short*)outv + (size_t)z * MM * CC;
        const bool do_rope = (z < 2);
        const float qscale = (z == 0) ? 0.125f : 1.0f;   // D^-0.5 folded into Q
        #pragma unroll
        for (int i = 0; i < 4; ++i) {
            const int m0 = mb + wr * 64 + i * 16 + (lane >> 4) * 4;
            #pragma unroll
            for (int j = 0; j < 4; ++j) {
                const int n = nb + wc * 64 + j * 16 + (lane & 15);
                const int h = n >> 6, d = n & 63;
                #pragma unroll
                for (int r = 0; r < 4; ++r) {
                    const int m  = m0 + r;
                    const int b_ = m >> 11, t = m & (TT - 1);
                    const float val     = acc[i][j][r];
                    const float partner = __shfl_xor(val, 1);
                    float r0, r1;
                    if (do_rope) {
                        const float2 cs = tab[t * 32 + (d >> 1)];
                        r0 = (val * cs.x - partner * cs.y) * qscale;
                        r1 = (val * cs.y + partner * cs.x) * qscale;
                    } else {
                        r0 = val; r1 = partner;
                    }
                    if ((lane & 1) == 0) {
                        const unsigned int pk =
                            (unsigned int)f2bf(r0) | ((unsigned int)f2bf(r1) << 16);
                        *(unsigned int*)&dst[(((size_t)(b_ * HH + h) * TT + t) * DD) + (d & ~1)] = pk;
                    }
                }
            }
        }
    }
}

// ---------------------------------------------------------------------------
// MFMA flash attention (causal), round-13: 8 waves x 128 q-rows per block
// (K/V stage amortized over 2x waves, 24 waves/CU cap), double-buffered K/V
// with register prefetch, defer-max rescale (THR=8), reversed dispatch,
// setprio around MFMA. Per-wave compute core identical to round-9/10 (HW-
// verified). Q arrives pre-scaled by D^-0.5.
// ---------------------------------------------------------------------------
__global__ __launch_bounds__(512) void attn_mfma(
    const unsigned short* __restrict__ qg, const unsigned short* __restrict__ kg,
    const unsigned short* __restrict__ vtg, unsigned short* __restrict__ att)
{
    __shared__ short Ks[2][64 * 64];   // [key][d], swizzled    (16 KB)
    __shared__ short Vs[2][64 * 64];   // [d][key], swizzled    (16 KB)
    __shared__ short Ps[8][16 * 64];   // per-wave [q][key]     (16 KB)

    const int tid  = threadIdx.x;           // 0..511
    const int lane = tid & 63;
    const int w    = tid >> 6;              // wave 0..7
    const int l15  = lane & 15, l4 = lane >> 4;
    const int jq   = 15 - blockIdx.x;       // reversed: big blocks first
    const int bh   = blockIdx.y;            // 0..63
    const int qb   = jq * 128;
    const int b_   = bh >> 4, h = bh & 15;
    const int my_diag = 2 * jq + (w >> 2);  // this wave's diagonal k-tile
    const int ntile   = 2 * jq + 2;

    const unsigned short* qrow = qg + ((size_t)bh * TT + qb + w * 16 + l15) * DD;
    const short8 qf0 = *(const short8*)(qrow + l4 * 8);
    const short8 qf1 = *(const short8*)(qrow + 32 + l4 * 8);

    f32x4 acc_o[4] = {};                     // [dj]: O[q=l4*4+r][d=dj*16+l15]
    float m_run[4] = {-1e30f, -1e30f, -1e30f, -1e30f};
    float l_run[4] = {};

    // staging: 512 threads, 1 short8 per matrix per tile
    const int srow = tid >> 3;               // 0..63
    const int sc0  = (tid & 7) * 8;          // 0..56
    const int bo0  = (srow * 128 + sc0 * 2) ^ ((srow & 7) << 4);
    const unsigned short* kst = kg  + ((size_t)bh * TT + srow) * DD + sc0;
    const unsigned short* vst = vtg + ((size_t)bh * DD + srow) * TT + sc0;

    // stage tile 0 directly
    {
        const short8 k0 = *(const short8*)(kst);
        const short8 v0 = *(const short8*)(vst);
        *(short8*)((char*)&Ks[0][0] + bo0) = k0;
        *(short8*)((char*)&Vs[0][0] + bo0) = v0;
    }
    __syncthreads();

    for (int kt = 0; kt < ntile; ++kt) {
        const int kb  = kt * 64;
        const int cur = kt & 1;
        const short* Kc = &Ks[cur][0];
        const short* Vc = &Vs[cur][0];

        // ---- issue next-tile loads (latency hides under compute) ----
        short8 nk, nv;
        const bool has_next = (kt + 1 < ntile);
        if (has_next) {
            nk = *(const short8*)(kst + (size_t)(kb + 64) * DD);
            nv = *(const short8*)(vst + kb + 64);
        }

        if (kt <= my_diag) {                 // waves past own diagonal idle
            // ---- QK^T: S[16 q][64 key] (Q pre-scaled) ----
            f32x4 s4[4];
            __builtin_amdgcn_s_setprio(1);
            #pragma unroll
            for (int kj = 0; kj < 4; ++kj) {
                const int key = kj * 16 + l15;
                const short8 kf0 = *(const short8*)((char*)Kc + ((key * 128 +      l4 * 16) ^ ((key & 7) << 4)));
                const short8 kf1 = *(const short8*)((char*)Kc + ((key * 128 + 64 + l4 * 16) ^ ((key & 7) << 4)));
                f32x4 zz = {};
                zz = __builtin_amdgcn_mfma_f32_16x16x32_bf16(qf0, kf0, zz, 0, 0, 0);
                zz = __builtin_amdgcn_mfma_f32_16x16x32_bf16(qf1, kf1, zz, 0, 0, 0);
                s4[kj] = zz;
            }
            __builtin_amdgcn_s_setprio(0);

            // ---- causal mask + tile max ----
            float p[4][4];                        // [kj][r]
            float tmax[4] = {-1e30f, -1e30f, -1e30f, -1e30f};
            const bool diag = (kt == my_diag);
            #pragma unroll
            for (int kj = 0; kj < 4; ++kj)
                #pragma unroll
                for (int r = 0; r < 4; ++r) {
                    float s = s4[kj][r];
                    if (diag) {
                        const int key_g = kb + kj * 16 + l15;
                        const int q_g   = qb + w * 16 + l4 * 4 + r;
                        if (key_g > q_g) s = -1e30f;
                    }
                    p[kj][r] = s;
                    tmax[r] = fmaxf(tmax[r], s);
                }
            #pragma unroll
            for (int mk = 1; mk < 16; mk <<= 1)
                #pragma unroll
                for (int r = 0; r < 4; ++r)
                    tmax[r] = fmaxf(tmax[r], __shfl_xor(tmax[r], mk));

            // ---- defer-max online softmax (THR=8) ----
            float grow = 0.f;
            #pragma unroll
            for (int r = 0; r < 4; ++r) grow = fmaxf(grow, tmax[r] - m_run[r]);
            if (__any(grow > 8.f)) {
                #pragma unroll
                for (int r = 0; r < 4; ++r) {
                    const float mn   = fmaxf(m_run[r], tmax[r]);
                    const float corr = __expf(m_run[r] - mn);
                    m_run[r] = mn;
                    l_run[r] *= corr;
                    #pragma unroll
                    for (int dj = 0; dj < 4; ++dj) acc_o[dj][r] *= corr;
                }
            }
            #pragma unroll
            for (int r = 0; r < 4; ++r) {
                float ls = 0.f;
                #pragma unroll
                for (int kj = 0; kj < 4; ++kj) {
                    const float e = __expf(p[kj][r] - m_run[r]);
                    p[kj][r] = e;
                    ls += e;
                }
                l_run[r] += ls;              // lane-partial; reduced at end
            }

            // ---- P -> LDS (bf16, A-frag layout source) ----
            #pragma unroll
            for (int kj = 0; kj < 4; ++kj)
                #pragma unroll
                for (int r = 0; r < 4; ++r) {
                    const int qr  = l4 * 4 + r;
                    const int key = kj * 16 + l15;
                    const int bo  = (qr * 128 + key * 2) ^ ((qr & 7) << 4);
                    *(short*)((char*)&Ps[w][0] + bo) = (short)f2bf(p[kj][r]);
                }

            // ---- PV: O += P (16x64) . V (64x64) ----
            const short8 pa0 = *(const short8*)((char*)&Ps[w][0] + ((l15 * 128 +      l4 * 16) ^ ((l15 & 7) << 4)));
            const short8 pa1 = *(const short8*)((char*)&Ps[w][0] + ((l15 * 128 + 64 + l4 * 16) ^ ((l15 & 7) << 4)));
            __builtin_amdgcn_s_setprio(1);
            #pragma unroll
            for (int dj = 0; dj < 4; ++dj) {
                const int dr = dj * 16 + l15;
                const short8 vf0 = *(const short8*)((char*)Vc + ((dr * 128 +      l4 * 16) ^ ((dr & 7) << 4)));
                const short8 vf1 = *(const short8*)((char*)Vc + ((dr * 128 + 64 + l4 * 16) ^ ((dr & 7) << 4)));
                acc_o[dj] = __builtin_amdgcn_mfma_f32_16x16x32_bf16(pa0, vf0, acc_o[dj], 0, 0, 0);
                acc_o[dj] = __builtin_amdgcn_mfma_f32_16x16x32_bf16(pa1, vf1, acc_o[dj], 0, 0, 0);
            }
            __builtin_amdgcn_s_setprio(0);
        }

        // ---- write prefetched tile into the other buffer ----
        if (has_next) {
            *(short8*)((char*)&Ks[cur ^ 1][0] + bo0) = nk;
            *(short8*)((char*)&Vs[cur ^ 1][0] + bo0) = nv;
        }
        __syncthreads();                     // next buffer visible; cur reusable
    }

    // ---- finalize: reduce l across the 16-lane axis, normalize, store ----
    #pragma unroll
    for (int mk = 1; mk < 16; mk <<= 1)
        #pragma unroll
        for (int r = 0; r < 4; ++r)
            l_run[r] += __shfl_xor(l_run[r], mk);

    #pragma unroll
    for (int r = 0; r < 4; ++r) {
        const float inv = 1.0f / l_run[r];
        const int t = qb + w * 16 + l4 * 4 + r;
        unsigned short* orow = att + ((size_t)(b_ * TT + t)) * CC + h * DD;
        #pragma unroll
        for (int dj = 0; dj < 4; ++dj)
            orow[dj * 16 + l15] = f2bf(acc_o[dj][r] * inv);
    }
}

// ---------------------------------------------------------------------------
extern "C" void kernel_launch(void* const* d_in, const int* in_sizes, int n_in,
                              void* d_out, int out_size, void* d_ws, size_t ws_size,
                              hipStream_t stream) {
    const float* x  = (const float*)d_in[0];
    const float* Wq = (const float*)d_in[1];
    const float* Wk = (const float*)d_in[2];
    const float* Wv = (const float*)d_in[3];
    const float* Wo = (const float*)d_in[4];
    const float* bo = (const float*)d_in[5];
    float* out = (float*)d_out;

    char* ws = (char*)d_ws;
    unsigned short* xb  = (unsigned short*)ws;                        // 16 MB (dead after QKV GEMM)
    unsigned short* aw  = xb;                                         // aliases xb (attn out)
    unsigned short* wt  = (unsigned short*)(ws + (16ull << 20));      //  8 MB (4x [N][K] bf16)
    unsigned short* qkv = (unsigned short*)(ws + (24ull << 20));      // 48 MB (q|k|v, [B][H][T][D])
    unsigned short* vt  = (unsigned short*)(ws + (72ull << 20));      // 16 MB ([bh][d][T])
    float2*         tab = (float2*)       (ws + (88ull << 20));       // 512 KB

    convert_x  <<<4096, 256, 0, stream>>>(x, xb);
    transpose_w<<<dim3(16, 16, 4), 256, 0, stream>>>(Wq, Wk, Wv, Wo, wt);
    rope_tables<<<256, 256, 0, stream>>>(tab);

    gemm_mfma<1><<<dim3(8, 64, 3), 256, 0, stream>>>(xb, wt, nullptr, tab, qkv);

    const size_t NEL = (size_t)MM * CC;
    transpose_v<<<dim3(8, 64), 256, 0, stream>>>(qkv + 2 * NEL, vt);

    attn_mfma<<<dim3(16, 64), 512, 0, stream>>>(qkv, qkv + NEL, vt, aw);

    gemm_mfma<0><<<dim3(8, 64), 256, 0, stream>>>(
        aw, wt + 3ull * CC * CC, bo, tab, out);
}